// Round 16
// baseline (290.872 us; speedup 1.0000x reference)
//
#include <hip/hip_runtime.h>
#include <math.h>

#define NB 64
#define NGRAPH 2000
#define EGRAPH 64000
#define NN (NB*NGRAPH)      // 128000
#define NE (NB*EGRAPH)      // 4096000
#define KSEL 1600
#define FEAT 10000
#define EMBD 64
#define G1D 32
#define G2D 32
#define DENSED 64
#define NCLSD 10
#define NCHUNK 8
#define CHUNK_E (EGRAPH/NCHUNK)   // 8000
#define NQD 8                     // dst-ranges per graph (scatter)
#define QNODES (NGRAPH/NQD)       // 250
#define LOUT_CAP 10000            // staging cap (avg 8000, +24 sigma)

// csr[] holds GRAPH-LOCAL byte offsets (src - g*2000)*64 — LDS half-row
// offsets — padded by 16 ints. (R15 bug: stored global src<<6, indexing a
// 128 KB graph-local LDS array with multi-MB offsets.)
// Graph->XCD ownership: graph g lives on XCD (g>>3).
// Aggregation: column-split LDS staging. W2 deferred past agg2 (linear),
// ReLU is per-column so agg1's epilogue stays splittable.

// ---------------------------------------------------------------------------
// K1a: per-chunk LDS histogram of dst. 8 blocks/graph x 256 threads.
// ---------------------------------------------------------------------------
__global__ __launch_bounds__(256) void chunk_hist(const int* __restrict__ ei,
                                                  int* __restrict__ chist)
{
    __shared__ int hist[NGRAPH];
    const int lb = blockIdx.x;           // 512 blocks
    const int xcd = lb & 7, t = lb >> 3; // t in [0,64)
    const int g = xcd * 8 + (t >> 3);
    const int q = t & 7;
    const int tid = threadIdx.x;
    const int base_e = g * EGRAPH + q * CHUNK_E;
    const int base_n = g * NGRAPH;
    for (int v = tid; v < NGRAPH; v += 256) hist[v] = 0;
    __syncthreads();
    for (int k = tid; k < CHUNK_E; k += 256) {
        int d = ei[NE + base_e + k];
        atomicAdd(&hist[d - base_n], 1);      // LDS atomic
    }
    __syncthreads();
    int* out = chist + (size_t)(g * NCHUNK + q) * NGRAPH;
    for (int v = tid; v < NGRAPH; v += 256) out[v] = hist[v];
}

// ---------------------------------------------------------------------------
// K1b: per-graph: deg = sum of 8 chunk hists -> dinv; exclusive scan ->
//      row_start. one block per graph.
// ---------------------------------------------------------------------------
__global__ __launch_bounds__(256) void scan_graph(const int* __restrict__ chist,
                                                  float* __restrict__ dinv,
                                                  int* __restrict__ row_start)
{
    __shared__ int hist[NGRAPH];
    __shared__ int csA[256];
    __shared__ int csB[256];
    const int b = (blockIdx.x & 7) * 8 + (blockIdx.x >> 3);   // XCD-local graph
    const int tid = threadIdx.x;
    const int base_n = b * NGRAPH, base_e = b * EGRAPH;
    const int* ch = chist + (size_t)b * NCHUNK * NGRAPH;

    for (int v = tid; v < NGRAPH; v += 256) {
        int tot = 0;
        #pragma unroll
        for (int q = 0; q < NCHUNK; ++q) tot += ch[q * NGRAPH + v];
        hist[v] = tot;
        dinv[base_n + v] = rsqrtf((float)(tot + 1));   // +1 self-loop
    }
    __syncthreads();
    if (tid < 250) {
        int s = 0;
        #pragma unroll
        for (int i = 0; i < 8; ++i) s += hist[tid * 8 + i];
        csA[tid] = s;
    }
    __syncthreads();
    int* sb = csA; int* db = csB;
    for (int off = 1; off < 256; off <<= 1) {
        int v = 0;
        if (tid < 250) { v = sb[tid]; if (tid >= off) v += sb[tid - off]; }
        if (tid < 250) db[tid] = v;
        __syncthreads();
        int* t = sb; sb = db; db = t;
    }
    if (tid < 250) {
        int run = (tid == 0) ? 0 : sb[tid - 1];
        #pragma unroll
        for (int i = 0; i < 8; ++i) {
            int idx = tid * 8 + i;
            int c = hist[idx];
            row_start[base_n + idx] = base_e + run;
            run += c;
        }
    }
}

// ---------------------------------------------------------------------------
// K1c: dst-range-partitioned scatter with LDS staging, 1024 threads/block.
// Stores GRAPH-LOCAL (src - base_n)*64 (LDS half-row byte offset).
// ---------------------------------------------------------------------------
__global__ __launch_bounds__(1024) void scatter_csr(const int* __restrict__ ei,
                                                    const int* __restrict__ row_start,
                                                    int* __restrict__ csr)
{
    __shared__ int cur[QNODES];
    __shared__ int lout[LOUT_CAP];
    const int lb = blockIdx.x;             // 512 blocks
    const int xcd = lb & 7, t = lb >> 3;   // t in [0,64)
    const int g = xcd * 8 + (t >> 3);
    const int qd = t & 7;
    const int tid = threadIdx.x;
    const int base_n = g * NGRAPH;
    const int lo = qd * QNODES;
    const int base = row_start[base_n + lo];
    const int qend = (g == NB - 1 && qd == NQD - 1) ? NE
                     : row_start[base_n + lo + QNODES];
    for (int v = tid; v < QNODES; v += 1024)
        cur[v] = row_start[base_n + lo + v] - base;
    __syncthreads();
    const int4* srcp = (const int4*)(ei + g * EGRAPH);
    const int4* dstp = (const int4*)(ei + NE + g * EGRAPH);
    const int sub = base_n + lo;
    for (int k = tid; k < EGRAPH / 4; k += 1024) {
        int4 d4 = dstp[k];
        int4 s4 = srcp[k];
        int d, pos;
        d = d4.x - sub;
        if ((unsigned)d < (unsigned)QNODES) {
            pos = atomicAdd(&cur[d], 1);
            if (pos < LOUT_CAP) lout[pos] = (s4.x - base_n) << 6;
        }
        d = d4.y - sub;
        if ((unsigned)d < (unsigned)QNODES) {
            pos = atomicAdd(&cur[d], 1);
            if (pos < LOUT_CAP) lout[pos] = (s4.y - base_n) << 6;
        }
        d = d4.z - sub;
        if ((unsigned)d < (unsigned)QNODES) {
            pos = atomicAdd(&cur[d], 1);
            if (pos < LOUT_CAP) lout[pos] = (s4.z - base_n) << 6;
        }
        d = d4.w - sub;
        if ((unsigned)d < (unsigned)QNODES) {
            pos = atomicAdd(&cur[d], 1);
            if (pos < LOUT_CAP) lout[pos] = (s4.w - base_n) << 6;
        }
    }
    __syncthreads();
    int size = qend - base;
    if (size > LOUT_CAP) size = LOUT_CAP;   // never in practice; keeps LDS safe
    for (int i = tid; i < size; i += 1024)
        csr[base + i] = lout[i];
}

// ---------------------------------------------------------------------------
// K2: embW = emb @ W1   (10000x64 @ 64x32)
// ---------------------------------------------------------------------------
__global__ __launch_bounds__(256) void embw_kernel(const float* __restrict__ emb,
                                                   const float* __restrict__ W1,
                                                   float* __restrict__ embW)
{
    __shared__ float W1s[EMBD * G1D];
    for (int i = threadIdx.x; i < EMBD * G1D; i += 256) W1s[i] = W1[i];
    __syncthreads();
    int id = blockIdx.x * 256 + threadIdx.x;
    int r = id >> 5, c = id & 31;
    if (r >= FEAT) return;
    const float* er = emb + r * EMBD;
    float acc = 0.f;
    #pragma unroll 8
    for (int k = 0; k < EMBD; ++k) acc += er[k] * W1s[k * G1D + c];
    embW[r * G1D + c] = acc;
}

// ---------------------------------------------------------------------------
// K3: A'[v] = dinv[v] * embW[x[v]]   (float4 lanes: 8 lanes per node)
// ---------------------------------------------------------------------------
__global__ __launch_bounds__(256) void gather_kernel(const int* __restrict__ x,
                                                     const float* __restrict__ embW,
                                                     const float* __restrict__ dinv,
                                                     float* __restrict__ A)
{
    int id = blockIdx.x * 256 + threadIdx.x;   // id = v*8 + r
    int v = id >> 3, r = id & 7;
    int xv = x[v];
    float dv = dinv[v];
    float4 e = ((const float4*)(embW + (size_t)xv * G1D))[r];
    e.x *= dv; e.y *= dv; e.z *= dv; e.w *= dv;
    ((float4*)(A + (size_t)v * G1D))[r] = e;
}

// ---------------------------------------------------------------------------
// K4: layer-1 aggregation, LDS-staged column half.
// Block (g,h,nh): stages cols [h*16,(h+1)*16) of graph g's A' (128 KB LDS),
// aggregates 1000 nodes' neighbors from LDS, writes C' = dv*relu(dv*agg+b1).
// grid 256 blocks (1/CU), 1024 threads; half-wave = 8 slots x 4 lanes(f4).
// ---------------------------------------------------------------------------
__global__ __launch_bounds__(1024) void agg1_lds(const float* __restrict__ Ain,
                                                 const float* __restrict__ dinv,
                                                 const int* __restrict__ row_start,
                                                 const int* __restrict__ csr,
                                                 const float* __restrict__ b1,
                                                 float* __restrict__ Cout)
{
    __shared__ float4 As4[NGRAPH * 4];     // 128 KB: 2000 x 64-B half-rows
    const int lb = blockIdx.x;             // 256 blocks
    const int xcd = lb & 7, t = lb >> 3;   // t 0..31
    const int g = xcd * 8 + (t >> 2);
    const int h = (t >> 1) & 1;
    const int nh = t & 1;
    const int tid = threadIdx.x;
    const int base_n = g * NGRAPH;
    {
        const float4* src4 = (const float4*)(Ain + (size_t)base_n * G1D);
        for (int i = tid; i < NGRAPH * 4; i += 1024) {
            int row = i >> 2, q = i & 3;
            As4[row * 4 + q] = src4[row * 8 + h * 4 + q];
        }
    }
    __syncthreads();
    const int hw = tid >> 5;       // half-wave 0..31
    const int hl = tid & 31;
    const int slot = hl >> 2;      // 0..7
    const int r = hl & 3;          // quad within 64-B half-row
    const int roff = r << 4;
    const char* Ab = (const char*)As4;
    const float4 bias4 = ((const float4*)b1)[h * 4 + r];

    // contiguous node chunk per half-wave: 1000 = 8*32 + 24*31
    const int c0 = nh * 1000 + hw * 31 + (hw < 8 ? hw : 8);
    const int cnt = 31 + (hw < 8 ? 1 : 0);
    int v = base_n + c0;
    int rs = row_start[v];
    int re = (v == NN - 1) ? NE : row_start[v + 1];
    int s0 = csr[rs + slot];
    int s1 = csr[rs + slot + 8];
    for (int i = 0; i < cnt; ++i) {
        int re_next = (v + 1 >= NN - 1) ? NE : row_start[v + 2];
        int n0 = csr[re + slot];
        int n1 = csr[re + slot + 8];
        int me = rs + ((re - rs) & ~15);
        float4 acc0 = make_float4(0.f, 0.f, 0.f, 0.f);
        float4 acc1 = make_float4(0.f, 0.f, 0.f, 0.f);
        if (slot == 0)
            acc0 = *(const float4*)(Ab + ((v - base_n) << 6) + roff); // self
        int j = rs + slot;
        while (j < me) {
            int jn = j + 16;
            int t0 = csr[jn];          // csr padded 16: safe
            int t1 = csr[jn + 8];
            float4 a0 = *(const float4*)(Ab + (unsigned)(s0 + roff));
            float4 a1 = *(const float4*)(Ab + (unsigned)(s1 + roff));
            acc0.x += a0.x; acc0.y += a0.y; acc0.z += a0.z; acc0.w += a0.w;
            acc1.x += a1.x; acc1.y += a1.y; acc1.z += a1.z; acc1.w += a1.w;
            j = jn; s0 = t0; s1 = t1;
        }
        {
            int jt = me + slot;
            if (jt < re) {
                float4 a = *(const float4*)(Ab + (unsigned)(s0 + roff));
                acc0.x += a.x; acc0.y += a.y; acc0.z += a.z; acc0.w += a.w;
            }
            if (jt + 8 < re) {
                float4 a = *(const float4*)(Ab + (unsigned)(s1 + roff));
                acc1.x += a.x; acc1.y += a.y; acc1.z += a.z; acc1.w += a.w;
            }
        }
        float4 acc;
        acc.x = acc0.x + acc1.x;
        acc.y = acc0.y + acc1.y;
        acc.z = acc0.z + acc1.z;
        acc.w = acc0.w + acc1.w;
        #pragma unroll
        for (int off = 4; off <= 16; off <<= 1) {   // reduce across 8 slots
            acc.x += __shfl_xor(acc.x, off, 32);
            acc.y += __shfl_xor(acc.y, off, 32);
            acc.z += __shfl_xor(acc.z, off, 32);
            acc.w += __shfl_xor(acc.w, off, 32);
        }
        float dv = dinv[v];
        if (slot == 0) {
            float4 o;
            o.x = dv * fmaxf(dv * acc.x + bias4.x, 0.f);
            o.y = dv * fmaxf(dv * acc.y + bias4.y, 0.f);
            o.z = dv * fmaxf(dv * acc.z + bias4.z, 0.f);
            o.w = dv * fmaxf(dv * acc.w + bias4.w, 0.f);
            ((float4*)(Cout + (size_t)v * G1D))[h * 4 + r] = o;
        }
        v = v + 1;
        rs = re; re = re_next; s0 = n0; s1 = n1;
    }
}

// ---------------------------------------------------------------------------
// K5: layer-2 aggregation, LDS-staged column half of C'.
// D[v] = dv * (sum C'[s] + C'[v])   (W2/bias/relu deferred to epi2)
// ---------------------------------------------------------------------------
__global__ __launch_bounds__(1024) void agg2_lds(const float* __restrict__ Cin,
                                                 const float* __restrict__ dinv,
                                                 const int* __restrict__ row_start,
                                                 const int* __restrict__ csr,
                                                 float* __restrict__ Dout)
{
    __shared__ float4 As4[NGRAPH * 4];
    const int lb = blockIdx.x;
    const int xcd = lb & 7, t = lb >> 3;
    const int g = xcd * 8 + (t >> 2);
    const int h = (t >> 1) & 1;
    const int nh = t & 1;
    const int tid = threadIdx.x;
    const int base_n = g * NGRAPH;
    {
        const float4* src4 = (const float4*)(Cin + (size_t)base_n * G1D);
        for (int i = tid; i < NGRAPH * 4; i += 1024) {
            int row = i >> 2, q = i & 3;
            As4[row * 4 + q] = src4[row * 8 + h * 4 + q];
        }
    }
    __syncthreads();
    const int hw = tid >> 5;
    const int hl = tid & 31;
    const int slot = hl >> 2;
    const int r = hl & 3;
    const int roff = r << 4;
    const char* Ab = (const char*)As4;

    const int c0 = nh * 1000 + hw * 31 + (hw < 8 ? hw : 8);
    const int cnt = 31 + (hw < 8 ? 1 : 0);
    int v = base_n + c0;
    int rs = row_start[v];
    int re = (v == NN - 1) ? NE : row_start[v + 1];
    int s0 = csr[rs + slot];
    int s1 = csr[rs + slot + 8];
    for (int i = 0; i < cnt; ++i) {
        int re_next = (v + 1 >= NN - 1) ? NE : row_start[v + 2];
        int n0 = csr[re + slot];
        int n1 = csr[re + slot + 8];
        int me = rs + ((re - rs) & ~15);
        float4 acc0 = make_float4(0.f, 0.f, 0.f, 0.f);
        float4 acc1 = make_float4(0.f, 0.f, 0.f, 0.f);
        if (slot == 0)
            acc0 = *(const float4*)(Ab + ((v - base_n) << 6) + roff);
        int j = rs + slot;
        while (j < me) {
            int jn = j + 16;
            int t0 = csr[jn];
            int t1 = csr[jn + 8];
            float4 a0 = *(const float4*)(Ab + (unsigned)(s0 + roff));
            float4 a1 = *(const float4*)(Ab + (unsigned)(s1 + roff));
            acc0.x += a0.x; acc0.y += a0.y; acc0.z += a0.z; acc0.w += a0.w;
            acc1.x += a1.x; acc1.y += a1.y; acc1.z += a1.z; acc1.w += a1.w;
            j = jn; s0 = t0; s1 = t1;
        }
        {
            int jt = me + slot;
            if (jt < re) {
                float4 a = *(const float4*)(Ab + (unsigned)(s0 + roff));
                acc0.x += a.x; acc0.y += a.y; acc0.z += a.z; acc0.w += a.w;
            }
            if (jt + 8 < re) {
                float4 a = *(const float4*)(Ab + (unsigned)(s1 + roff));
                acc1.x += a.x; acc1.y += a.y; acc1.z += a.z; acc1.w += a.w;
            }
        }
        float4 acc;
        acc.x = acc0.x + acc1.x;
        acc.y = acc0.y + acc1.y;
        acc.z = acc0.z + acc1.z;
        acc.w = acc0.w + acc1.w;
        #pragma unroll
        for (int off = 4; off <= 16; off <<= 1) {
            acc.x += __shfl_xor(acc.x, off, 32);
            acc.y += __shfl_xor(acc.y, off, 32);
            acc.z += __shfl_xor(acc.z, off, 32);
            acc.w += __shfl_xor(acc.w, off, 32);
        }
        float dv = dinv[v];
        if (slot == 0) {
            float4 o;
            o.x = dv * acc.x; o.y = dv * acc.y;
            o.z = dv * acc.z; o.w = dv * acc.w;
            ((float4*)(Dout + (size_t)v * G1D))[h * 4 + r] = o;
        }
        v = v + 1;
        rs = re; re = re_next; s0 = n0; s1 = n1;
    }
}

// ---------------------------------------------------------------------------
// K5b: epilogue: h2 = relu(D @ W2 + b2); score = tanh(h2.pw/||pw||).
// Streaming, 512 blocks x 256 thr; half-wave per row.
// ---------------------------------------------------------------------------
__global__ __launch_bounds__(256) void epi2(const float* __restrict__ D,
                                            const float* __restrict__ W2,
                                            const float* __restrict__ b2,
                                            const float* __restrict__ pool_w,
                                            float* __restrict__ h2out,
                                            float* __restrict__ scores)
{
    __shared__ float W2s[G1D * G2D];
    for (int i = threadIdx.x; i < G1D * G2D; i += 256) W2s[i] = W2[i];
    __syncthreads();
    const int lb = blockIdx.x;             // 512 blocks
    const int xcd = lb & 7, t = lb >> 3;   // t 0..63
    const int g = xcd * 8 + (t >> 3);
    const int seg = t & 7;
    const int hw = threadIdx.x >> 5;       // 0..7
    const int hl = threadIdx.x & 31;
    const int r = hl & 7;
    const int base_n = g * NGRAPH;
    const float b2l = b2[hl];
    const float pwl = pool_w[hl];
    float nsq = pwl * pwl;
    #pragma unroll
    for (int off = 16; off; off >>= 1) nsq += __shfl_xor(nsq, off, 32);
    const float inv_norm = rsqrtf(nsq);

    for (int i = hw; i < QNODES; i += 8) {
        int v = base_n + seg * QNODES + i;
        float4 E = ((const float4*)(D + (size_t)v * G1D))[r];
        float z = 0.f;
        #pragma unroll
        for (int k = 0; k < G1D; ++k) {
            float hk;
            switch (k & 3) {
                case 0: hk = __shfl(E.x, k >> 2, 32); break;
                case 1: hk = __shfl(E.y, k >> 2, 32); break;
                case 2: hk = __shfl(E.z, k >> 2, 32); break;
                default: hk = __shfl(E.w, k >> 2, 32); break;
            }
            z += hk * W2s[k * G2D + hl];
        }
        float h2v = fmaxf(z + b2l, 0.f);
        h2out[(size_t)v * G2D + hl] = h2v;
        float sc = h2v * pwl;
        #pragma unroll
        for (int off = 16; off; off >>= 1) sc += __shfl_xor(sc, off, 32);
        if (hl == 0) scores[v] = tanhf(sc * inv_norm);
    }
}

// ---------------------------------------------------------------------------
// K6: per-graph top-K(1600 of 2000) via 4-pass radix-256 select + parallel
// scaled max-pool + dense MLP. one block per graph, 256 threads.
// ---------------------------------------------------------------------------
__global__ __launch_bounds__(256) void topk_pool_mlp(const float* __restrict__ h2,
                                                     const float* __restrict__ scores,
                                                     const float* __restrict__ dense_W,
                                                     const float* __restrict__ dense_b,
                                                     const float* __restrict__ out_W,
                                                     const float* __restrict__ out_b,
                                                     float* __restrict__ out)
{
    __shared__ unsigned keys[NGRAPH];
    __shared__ float    sval[NGRAPH];
    __shared__ unsigned char inc[NGRAPH];
    __shared__ int  hist[256];
    __shared__ int  csA[256];
    __shared__ int  csB[256];
    __shared__ int  sel[2];              // [0]=d*, [1]=count strictly above d*
    __shared__ int  redc[4];
    __shared__ float redf[32][32];
    __shared__ float gvec[32];
    __shared__ float dvec[DENSED];
    const int b = (blockIdx.x & 7) * 8 + (blockIdx.x >> 3);   // XCD-local graph
    const int tid = threadIdx.x;
    const int base_n = b * NGRAPH;

    for (int v = tid; v < NGRAPH; v += 256) {
        float f = scores[base_n + v];
        sval[v] = f;
        unsigned u = __float_as_uint(f);
        keys[v] = (u & 0x80000000u) ? ~u : (u | 0x80000000u);  // monotone map
    }
    __syncthreads();

    unsigned T = 0;
    int need = KSEL;
    #pragma unroll
    for (int pass = 0; pass < 4; ++pass) {
        const int s = 24 - pass * 8;
        const unsigned hi_mask = (pass == 0) ? 0u : (0xFFFFFFFFu << (s + 8));
        hist[tid] = 0;
        __syncthreads();
        for (int v = tid; v < NGRAPH; v += 256) {
            unsigned k = keys[v];
            if ((k & hi_mask) == (T & hi_mask))
                atomicAdd(&hist[(k >> s) & 255], 1);
        }
        __syncthreads();
        csA[tid] = hist[255 - tid];
        __syncthreads();
        int* sb = csA; int* db = csB;
        for (int off = 1; off < 256; off <<= 1) {
            int val = sb[tid];
            if (tid >= off) val += sb[tid - off];
            db[tid] = val;
            __syncthreads();
            int* t = sb; sb = db; db = t;
        }
        {
            const int d = tid;
            int suf_d = sb[255 - d];
            int suf_d1 = (d == 255) ? 0 : sb[254 - d];
            if (suf_d >= need && suf_d1 < need) {
                sel[0] = d;
                sel[1] = suf_d1;
            }
        }
        __syncthreads();
        T |= ((unsigned)sel[0]) << s;
        need -= sel[1];
        __syncthreads();
    }

    const int wid = tid >> 6, ln = tid & 63;
    int cg = 0, ce = 0;
    for (int v = tid; v < NGRAPH; v += 256) {
        cg += (keys[v] > T) ? 1 : 0;
        ce += (keys[v] == T) ? 1 : 0;
    }
    int packed = (cg << 16) | ce;
    #pragma unroll
    for (int off = 32; off; off >>= 1) packed += __shfl_down(packed, off, 64);
    if (ln == 0) redc[wid] = packed;
    __syncthreads();
    int tot = redc[0] + redc[1] + redc[2] + redc[3];
    int m_gt = tot >> 16, m_eq = tot & 0xffff;
    int needed = KSEL - m_gt;
    float fT = (T & 0x80000000u) ? __uint_as_float(T & 0x7fffffffu)
                                 : __uint_as_float(~T);
    if (m_eq == needed || fT == 0.0f) {
        for (int v = tid; v < NGRAPH; v += 256) inc[v] = (keys[v] >= T) ? 1 : 0;
    } else {
        if (tid == 0) {
            int take = 0;
            for (int v = 0; v < NGRAPH; ++v) {
                unsigned k = keys[v];
                if (k > T) inc[v] = 1;
                else if (k == T && take < needed) { inc[v] = 1; ++take; }
                else inc[v] = 0;
            }
        }
    }
    __syncthreads();

    {
        const int rowslot = tid >> 3;
        const int c4 = tid & 7;
        float4 m4 = make_float4(-INFINITY, -INFINITY, -INFINITY, -INFINITY);
        for (int v = rowslot; v < NGRAPH; v += 32) {
            float4 hrow = ((const float4*)(h2 + (size_t)(base_n + v) * G2D))[c4];
            float sv = inc[v] ? sval[v] : 0.f;
            float big = inc[v] ? 0.f : -INFINITY;
            m4.x = fmaxf(m4.x, sv * hrow.x + big);
            m4.y = fmaxf(m4.y, sv * hrow.y + big);
            m4.z = fmaxf(m4.z, sv * hrow.z + big);
            m4.w = fmaxf(m4.w, sv * hrow.w + big);
        }
        redf[rowslot][c4 * 4 + 0] = m4.x;
        redf[rowslot][c4 * 4 + 1] = m4.y;
        redf[rowslot][c4 * 4 + 2] = m4.z;
        redf[rowslot][c4 * 4 + 3] = m4.w;
    }
    __syncthreads();
    if (tid < 32) {
        float g = redf[0][tid];
        #pragma unroll
        for (int rr = 1; rr < 32; ++rr) g = fmaxf(g, redf[rr][tid]);
        gvec[tid] = g;
    }
    __syncthreads();
    if (tid < DENSED) {
        float t = dense_b[tid];
        #pragma unroll
        for (int k = 0; k < G2D; ++k) t += gvec[k] * dense_W[k * DENSED + tid];
        dvec[tid] = fmaxf(t, 0.f);
    }
    __syncthreads();
    if (tid < NCLSD) {
        float o = out_b[tid];
        #pragma unroll
        for (int j = 0; j < DENSED; ++j) o += dvec[j] * out_W[j * NCLSD + tid];
        out[b * NCLSD + tid] = o;
    }
}

// ---------------------------------------------------------------------------
extern "C" void kernel_launch(void* const* d_in, const int* in_sizes, int n_in,
                              void* d_out, int out_size, void* d_ws, size_t ws_size,
                              hipStream_t stream)
{
    (void)in_sizes; (void)n_in; (void)out_size; (void)ws_size;
    const int*   x       = (const int*)  d_in[0];
    const int*   edge    = (const int*)  d_in[1];
    const float* emb     = (const float*)d_in[3];
    const float* W1      = (const float*)d_in[4];
    const float* b1      = (const float*)d_in[5];
    const float* W2      = (const float*)d_in[6];
    const float* b2      = (const float*)d_in[7];
    const float* pool_w  = (const float*)d_in[8];
    const float* dense_W = (const float*)d_in[9];
    const float* dense_b = (const float*)d_in[10];
    const float* out_W   = (const float*)d_in[11];
    const float* out_b   = (const float*)d_in[12];
    float* outp = (float*)d_out;

    // workspace carve-up (~53 MB)
    float* embW      = (float*)d_ws;                 // FEAT*32
    float* Abuf      = embW + FEAT * G1D;            // N*32 (A', then D)
    float* Bbuf      = Abuf + (size_t)NN * G1D;      // N*32 (chist, C', then h2)
    float* dinv      = Bbuf + (size_t)NN * G2D;      // N
    int*   row_start = (int*)(dinv + NN);            // N
    int*   csr       = row_start + NN;               // E (+16 pad)
    float* scores    = (float*)(csr + NE + 16);      // N

    int* chist = (int*)Bbuf;                         // NB*8*NGRAPH = 1024000

    chunk_hist<<<NB * NCHUNK, 256, 0, stream>>>(edge, chist);
    scan_graph<<<NB, 256, 0, stream>>>(chist, dinv, row_start);
    scatter_csr<<<NB * NQD, 1024, 0, stream>>>(edge, row_start, csr);
    embw_kernel<<<(FEAT * G1D) / 256, 256, 0, stream>>>(emb, W1, embW);
    gather_kernel<<<(NN * 8) / 256, 256, 0, stream>>>(x, embW, dinv, Abuf);
    agg1_lds<<<NB * 4, 1024, 0, stream>>>(Abuf, dinv, row_start, csr, b1, Bbuf);
    agg2_lds<<<NB * 4, 1024, 0, stream>>>(Bbuf, dinv, row_start, csr, Abuf);
    epi2<<<NB * 8, 256, 0, stream>>>(Abuf, W2, b2, pool_w, Bbuf, scores);
    topk_pool_mlp<<<NB, 256, 0, stream>>>(Bbuf, scores, dense_W, dense_b, out_W, out_b, outp);
}

// Round 17
// 247.649 us; speedup vs baseline: 1.1745x; 1.1745x over previous
//
#include <hip/hip_runtime.h>
#include <math.h>

#define NB 64
#define NGRAPH 2000
#define EGRAPH 64000
#define NN (NB*NGRAPH)      // 128000
#define NE (NB*EGRAPH)      // 4096000
#define KSEL 1600
#define FEAT 10000
#define EMBD 64
#define G1D 32
#define G2D 32
#define DENSED 64
#define NCLSD 10
#define NCHUNK 8
#define CHUNK_E (EGRAPH/NCHUNK)   // 8000
#define NQD 8                     // dst-ranges per graph (scatter)
#define QNODES (NGRAPH/NQD)       // 250
#define LOUT_CAP 10000            // staging cap (avg 8000, +24 sigma)

// R14 pipeline (best: 254 us), launches fused 8 -> 6:
//   prep  = chunk_hist (512 blocks) + embw (1250 blocks)     [independent]
//   scan
//   mid   = scatter_csr (512 blocks) + gather (1000 blocks)  [independent]
//   agg1, agg2, topk
// csr[] holds GLOBAL row byte offsets (src*128), padded by 16 ints.
// Graph->XCD ownership: graph g lives on XCD (g>>3).

// ---------------------------------------------------------------------------
// K1: prep = per-chunk LDS histogram of dst (blocks 0..511)
//          + embW = emb @ W1 (blocks 512..1761). 256 threads.
// ---------------------------------------------------------------------------
__global__ __launch_bounds__(256) void prep_kernel(const int* __restrict__ ei,
                                                   int* __restrict__ chist,
                                                   const float* __restrict__ emb,
                                                   const float* __restrict__ W1,
                                                   float* __restrict__ embW)
{
    __shared__ float shmem[2048];        // 8 KB union: hist[2000] / W1s[2048]
    const int tid = threadIdx.x;
    if (blockIdx.x < 512) {
        int* hist = (int*)shmem;
        const int lb = blockIdx.x;           // 512 blocks
        const int xcd = lb & 7, t = lb >> 3; // t in [0,64)
        const int g = xcd * 8 + (t >> 3);
        const int q = t & 7;
        const int base_e = g * EGRAPH + q * CHUNK_E;
        const int base_n = g * NGRAPH;
        for (int v = tid; v < NGRAPH; v += 256) hist[v] = 0;
        __syncthreads();
        for (int k = tid; k < CHUNK_E; k += 256) {
            int d = ei[NE + base_e + k];
            atomicAdd(&hist[d - base_n], 1);      // LDS atomic
        }
        __syncthreads();
        int* out = chist + (size_t)(g * NCHUNK + q) * NGRAPH;
        for (int v = tid; v < NGRAPH; v += 256) out[v] = hist[v];
    } else {
        float* W1s = shmem;
        for (int i = tid; i < EMBD * G1D; i += 256) W1s[i] = W1[i];
        __syncthreads();
        int id = (blockIdx.x - 512) * 256 + tid;
        int r = id >> 5, c = id & 31;
        if (r >= FEAT) return;
        const float* er = emb + r * EMBD;
        float acc = 0.f;
        #pragma unroll 8
        for (int k = 0; k < EMBD; ++k) acc += er[k] * W1s[k * G1D + c];
        embW[r * G1D + c] = acc;
    }
}

// ---------------------------------------------------------------------------
// K2: per-graph: deg = sum of 8 chunk hists -> dinv; exclusive scan ->
//      row_start. one block per graph.
// ---------------------------------------------------------------------------
__global__ __launch_bounds__(256) void scan_graph(const int* __restrict__ chist,
                                                  float* __restrict__ dinv,
                                                  int* __restrict__ row_start)
{
    __shared__ int hist[NGRAPH];
    __shared__ int csA[256];
    __shared__ int csB[256];
    const int b = (blockIdx.x & 7) * 8 + (blockIdx.x >> 3);   // XCD-local graph
    const int tid = threadIdx.x;
    const int base_n = b * NGRAPH, base_e = b * EGRAPH;
    const int* ch = chist + (size_t)b * NCHUNK * NGRAPH;

    for (int v = tid; v < NGRAPH; v += 256) {
        int tot = 0;
        #pragma unroll
        for (int q = 0; q < NCHUNK; ++q) tot += ch[q * NGRAPH + v];
        hist[v] = tot;
        dinv[base_n + v] = rsqrtf((float)(tot + 1));   // +1 self-loop
    }
    __syncthreads();
    if (tid < 250) {
        int s = 0;
        #pragma unroll
        for (int i = 0; i < 8; ++i) s += hist[tid * 8 + i];
        csA[tid] = s;
    }
    __syncthreads();
    int* sb = csA; int* db = csB;
    for (int off = 1; off < 256; off <<= 1) {
        int v = 0;
        if (tid < 250) { v = sb[tid]; if (tid >= off) v += sb[tid - off]; }
        if (tid < 250) db[tid] = v;
        __syncthreads();
        int* t = sb; sb = db; db = t;
    }
    if (tid < 250) {
        int run = (tid == 0) ? 0 : sb[tid - 1];
        #pragma unroll
        for (int i = 0; i < 8; ++i) {
            int idx = tid * 8 + i;
            int c = hist[idx];
            row_start[base_n + idx] = base_e + run;
            run += c;
        }
    }
}

// ---------------------------------------------------------------------------
// K3: mid = dst-range scatter with LDS staging (blocks 0..511)
//         + A' gather (blocks 512..1511). 1024 threads.
// scatter stores GLOBAL byte offset src*128.
// ---------------------------------------------------------------------------
__global__ __launch_bounds__(1024) void mid_kernel(const int* __restrict__ ei,
                                                   const int* __restrict__ row_start,
                                                   int* __restrict__ csr,
                                                   const int* __restrict__ x,
                                                   const float* __restrict__ embW,
                                                   const float* __restrict__ dinv,
                                                   float* __restrict__ A)
{
    __shared__ int cur[QNODES];
    __shared__ int lout[LOUT_CAP];
    const int tid = threadIdx.x;
    if (blockIdx.x < 512) {
        const int lb = blockIdx.x;             // 512 blocks
        const int xcd = lb & 7, t = lb >> 3;   // t in [0,64)
        const int g = xcd * 8 + (t >> 3);
        const int qd = t & 7;
        const int base_n = g * NGRAPH;
        const int lo = qd * QNODES;
        const int base = row_start[base_n + lo];
        const int qend = (g == NB - 1 && qd == NQD - 1) ? NE
                         : row_start[base_n + lo + QNODES];
        for (int v = tid; v < QNODES; v += 1024)
            cur[v] = row_start[base_n + lo + v] - base;
        __syncthreads();
        const int4* srcp = (const int4*)(ei + g * EGRAPH);
        const int4* dstp = (const int4*)(ei + NE + g * EGRAPH);
        const int sub = base_n + lo;
        for (int k = tid; k < EGRAPH / 4; k += 1024) {
            int4 d4 = dstp[k];
            int4 s4 = srcp[k];
            int d, pos;
            d = d4.x - sub;
            if ((unsigned)d < (unsigned)QNODES) {
                pos = atomicAdd(&cur[d], 1);
                if (pos < LOUT_CAP) lout[pos] = s4.x << 7;
            }
            d = d4.y - sub;
            if ((unsigned)d < (unsigned)QNODES) {
                pos = atomicAdd(&cur[d], 1);
                if (pos < LOUT_CAP) lout[pos] = s4.y << 7;
            }
            d = d4.z - sub;
            if ((unsigned)d < (unsigned)QNODES) {
                pos = atomicAdd(&cur[d], 1);
                if (pos < LOUT_CAP) lout[pos] = s4.z << 7;
            }
            d = d4.w - sub;
            if ((unsigned)d < (unsigned)QNODES) {
                pos = atomicAdd(&cur[d], 1);
                if (pos < LOUT_CAP) lout[pos] = s4.w << 7;
            }
        }
        __syncthreads();
        int size = qend - base;
        if (size > LOUT_CAP) size = LOUT_CAP;   // safety clamp
        for (int i = tid; i < size; i += 1024)
            csr[base + i] = lout[i];
    } else {
        int id = (blockIdx.x - 512) * 1024 + tid;   // id = v*8 + r
        int v = id >> 3, r = id & 7;
        int xv = x[v];
        float dv = dinv[v];
        float4 e = ((const float4*)(embW + (size_t)xv * G1D))[r];
        e.x *= dv; e.y *= dv; e.z *= dv; e.w *= dv;
        ((float4*)(A + (size_t)v * G1D))[r] = e;
    }
}

// ---------------------------------------------------------------------------
// agg: half-wave (32 lanes) per node, 4 edge-slots x 8 lanes x float4,
// depth-2 pipeline + rolling next-node prefetch (R14, proven).
// csr entries are pre-shifted global byte offsets; csr padded 16.
// ---------------------------------------------------------------------------

// K4: layer-1 aggregation + ReLU + (h1 @ W2) * dinv -> B'
__global__ __launch_bounds__(256) void agg1_kernel(const float* __restrict__ Ain,
                                                   const float* __restrict__ dinv,
                                                   const int* __restrict__ row_start,
                                                   const int* __restrict__ csr,
                                                   const float* __restrict__ b1,
                                                   const float* __restrict__ W2,
                                                   float* __restrict__ Bout)
{
    __shared__ float W2s[G1D * G2D];
    for (int i = threadIdx.x; i < G1D * G2D; i += 256) W2s[i] = W2[i];
    __syncthreads();
    const int lb = blockIdx.x;
    const int xcd = lb & 7, idx = lb >> 3;
    const int b = xcd * 8 + (idx >> 5);     // graph
    const int blk = idx & 31;
    const int half = threadIdx.x >> 5;      // 0..7
    const int hl = threadIdx.x & 31;        // lane in half-wave
    const int slot = hl >> 3;               // 0..3 edge slot
    const int r = hl & 7;                   // column quad: cols 4r..4r+3
    const int roff = r << 4;                // byte offset within row
    const char* Abase = (const char*)Ain;
    const int base_n = b * NGRAPH;
    const float4 bias4 = ((const float4*)b1)[r];

    const int vloc0 = blk * 64 + half * 8;
    int v = base_n + ((vloc0 < NGRAPH) ? vloc0 : NGRAPH - 1);
    int rs = row_start[v];
    int re = (v == NN - 1) ? NE : row_start[v + 1];
    int s0 = csr[rs + slot];
    int s1 = csr[rs + slot + 4];

    for (int i = 0; i < 8; ++i) {
        int vloc = vloc0 + i;
        if (vloc >= NGRAPH) break;
        int re_next = (v + 1 >= NN - 1) ? NE : row_start[v + 2];
        int n0 = csr[re + slot];
        int n1 = csr[re + slot + 4];

        int me = rs + ((re - rs) & ~7);     // unpredicated region end
        float4 acc0 = make_float4(0.f, 0.f, 0.f, 0.f);
        float4 acc1 = make_float4(0.f, 0.f, 0.f, 0.f);
        if (slot == 0)
            acc0 = ((const float4*)(Ain + (size_t)v * G1D))[r];   // self-loop
        int j = rs + slot;
        while (j < me) {
            int jn = j + 8;
            int t0 = csr[jn];               // unguarded 2-ahead (csr padded)
            int t1 = csr[jn + 4];
            float4 a0 = *(const float4*)(Abase + (unsigned)(s0 + roff));
            float4 a1 = *(const float4*)(Abase + (unsigned)(s1 + roff));
            acc0.x += a0.x; acc0.y += a0.y; acc0.z += a0.z; acc0.w += a0.w;
            acc1.x += a1.x; acc1.y += a1.y; acc1.z += a1.z; acc1.w += a1.w;
            j = jn; s0 = t0; s1 = t1;
        }
        {
            int jt = me + slot;
            if (jt < re) {
                float4 a = *(const float4*)(Abase + (unsigned)(s0 + roff));
                acc0.x += a.x; acc0.y += a.y; acc0.z += a.z; acc0.w += a.w;
            }
            if (jt + 4 < re) {
                float4 a = *(const float4*)(Abase + (unsigned)(s1 + roff));
                acc1.x += a.x; acc1.y += a.y; acc1.z += a.z; acc1.w += a.w;
            }
        }
        float4 acc;
        acc.x = acc0.x + acc1.x;
        acc.y = acc0.y + acc1.y;
        acc.z = acc0.z + acc1.z;
        acc.w = acc0.w + acc1.w;
        #pragma unroll
        for (int off = 8; off <= 16; off <<= 1) {
            acc.x += __shfl_xor(acc.x, off, 32);
            acc.y += __shfl_xor(acc.y, off, 32);
            acc.z += __shfl_xor(acc.z, off, 32);
            acc.w += __shfl_xor(acc.w, off, 32);
        }
        float dv = dinv[v];
        float4 h4;
        h4.x = fmaxf(dv * acc.x + bias4.x, 0.f);
        h4.y = fmaxf(dv * acc.y + bias4.y, 0.f);
        h4.z = fmaxf(dv * acc.z + bias4.z, 0.f);
        h4.w = fmaxf(dv * acc.w + bias4.w, 0.f);
        float o = 0.f;
        #pragma unroll
        for (int k = 0; k < G1D; ++k) {
            float hk;
            switch (k & 3) {
                case 0: hk = __shfl(h4.x, k >> 2, 32); break;
                case 1: hk = __shfl(h4.y, k >> 2, 32); break;
                case 2: hk = __shfl(h4.z, k >> 2, 32); break;
                default: hk = __shfl(h4.w, k >> 2, 32); break;
            }
            o += hk * W2s[k * G2D + hl];
        }
        Bout[(size_t)v * G2D + hl] = dv * o;
        v = v + 1;
        rs = re; re = re_next; s0 = n0; s1 = n1;
    }
}

// K5: layer-2 aggregation + ReLU -> h2 ; score = tanh(h2 . pw / ||pw||)
__global__ __launch_bounds__(256) void agg2_kernel(const float* __restrict__ Bin,
                                                   const float* __restrict__ dinv,
                                                   const int* __restrict__ row_start,
                                                   const int* __restrict__ csr,
                                                   const float* __restrict__ b2,
                                                   const float* __restrict__ pool_w,
                                                   float* __restrict__ h2out,
                                                   float* __restrict__ scores)
{
    const int lb = blockIdx.x;
    const int xcd = lb & 7, idx = lb >> 3;
    const int b = xcd * 8 + (idx >> 5);
    const int blk = idx & 31;
    const int half = threadIdx.x >> 5;
    const int hl = threadIdx.x & 31;
    const int slot = hl >> 3;
    const int r = hl & 7;
    const int roff = r << 4;
    const char* Bbase = (const char*)Bin;
    const int base_n = b * NGRAPH;
    const float4 bias4 = ((const float4*)b2)[r];
    const float4 pw4 = ((const float4*)pool_w)[r];

    float pw = pool_w[hl];
    float nsq = pw * pw;
    #pragma unroll
    for (int off = 16; off; off >>= 1) nsq += __shfl_xor(nsq, off, 32);
    const float inv_norm = rsqrtf(nsq);

    const int vloc0 = blk * 64 + half * 8;
    int v = base_n + ((vloc0 < NGRAPH) ? vloc0 : NGRAPH - 1);
    int rs = row_start[v];
    int re = (v == NN - 1) ? NE : row_start[v + 1];
    int s0 = csr[rs + slot];
    int s1 = csr[rs + slot + 4];

    for (int i = 0; i < 8; ++i) {
        int vloc = vloc0 + i;
        if (vloc >= NGRAPH) break;
        int re_next = (v + 1 >= NN - 1) ? NE : row_start[v + 2];
        int n0 = csr[re + slot];
        int n1 = csr[re + slot + 4];

        int me = rs + ((re - rs) & ~7);
        float4 acc0 = make_float4(0.f, 0.f, 0.f, 0.f);
        float4 acc1 = make_float4(0.f, 0.f, 0.f, 0.f);
        if (slot == 0)
            acc0 = ((const float4*)(Bin + (size_t)v * G2D))[r];
        int j = rs + slot;
        while (j < me) {
            int jn = j + 8;
            int t0 = csr[jn];
            int t1 = csr[jn + 4];
            float4 a0 = *(const float4*)(Bbase + (unsigned)(s0 + roff));
            float4 a1 = *(const float4*)(Bbase + (unsigned)(s1 + roff));
            acc0.x += a0.x; acc0.y += a0.y; acc0.z += a0.z; acc0.w += a0.w;
            acc1.x += a1.x; acc1.y += a1.y; acc1.z += a1.z; acc1.w += a1.w;
            j = jn; s0 = t0; s1 = t1;
        }
        {
            int jt = me + slot;
            if (jt < re) {
                float4 a = *(const float4*)(Bbase + (unsigned)(s0 + roff));
                acc0.x += a.x; acc0.y += a.y; acc0.z += a.z; acc0.w += a.w;
            }
            if (jt + 4 < re) {
                float4 a = *(const float4*)(Bbase + (unsigned)(s1 + roff));
                acc1.x += a.x; acc1.y += a.y; acc1.z += a.z; acc1.w += a.w;
            }
        }
        float4 acc;
        acc.x = acc0.x + acc1.x;
        acc.y = acc0.y + acc1.y;
        acc.z = acc0.z + acc1.z;
        acc.w = acc0.w + acc1.w;
        #pragma unroll
        for (int off = 8; off <= 16; off <<= 1) {
            acc.x += __shfl_xor(acc.x, off, 32);
            acc.y += __shfl_xor(acc.y, off, 32);
            acc.z += __shfl_xor(acc.z, off, 32);
            acc.w += __shfl_xor(acc.w, off, 32);
        }
        float dv = dinv[v];
        float4 h4;
        h4.x = fmaxf(dv * acc.x + bias4.x, 0.f);
        h4.y = fmaxf(dv * acc.y + bias4.y, 0.f);
        h4.z = fmaxf(dv * acc.z + bias4.z, 0.f);
        h4.w = fmaxf(dv * acc.w + bias4.w, 0.f);
        if (slot == 0)
            ((float4*)(h2out + (size_t)v * G2D))[r] = h4;
        float t = h4.x * pw4.x + h4.y * pw4.y + h4.z * pw4.z + h4.w * pw4.w;
        t += __shfl_xor(t, 1, 32);
        t += __shfl_xor(t, 2, 32);
        t += __shfl_xor(t, 4, 32);
        if (hl == 0) scores[v] = tanhf(t * inv_norm);
        v = v + 1;
        rs = re; re = re_next; s0 = n0; s1 = n1;
    }
}

// ---------------------------------------------------------------------------
// K6: per-graph top-K(1600 of 2000) via 4-pass radix-256 select + parallel
// scaled max-pool + dense MLP. one block per graph, 256 threads.
// ---------------------------------------------------------------------------
__global__ __launch_bounds__(256) void topk_pool_mlp(const float* __restrict__ h2,
                                                     const float* __restrict__ scores,
                                                     const float* __restrict__ dense_W,
                                                     const float* __restrict__ dense_b,
                                                     const float* __restrict__ out_W,
                                                     const float* __restrict__ out_b,
                                                     float* __restrict__ out)
{
    __shared__ unsigned keys[NGRAPH];
    __shared__ float    sval[NGRAPH];
    __shared__ unsigned char inc[NGRAPH];
    __shared__ int  hist[256];
    __shared__ int  csA[256];
    __shared__ int  csB[256];
    __shared__ int  sel[2];
    __shared__ int  redc[4];
    __shared__ float redf[32][32];
    __shared__ float gvec[32];
    __shared__ float dvec[DENSED];
    const int b = (blockIdx.x & 7) * 8 + (blockIdx.x >> 3);   // XCD-local graph
    const int tid = threadIdx.x;
    const int base_n = b * NGRAPH;

    for (int v = tid; v < NGRAPH; v += 256) {
        float f = scores[base_n + v];
        sval[v] = f;
        unsigned u = __float_as_uint(f);
        keys[v] = (u & 0x80000000u) ? ~u : (u | 0x80000000u);  // monotone map
    }
    __syncthreads();

    unsigned T = 0;
    int need = KSEL;
    #pragma unroll
    for (int pass = 0; pass < 4; ++pass) {
        const int s = 24 - pass * 8;
        const unsigned hi_mask = (pass == 0) ? 0u : (0xFFFFFFFFu << (s + 8));
        hist[tid] = 0;
        __syncthreads();
        for (int v = tid; v < NGRAPH; v += 256) {
            unsigned k = keys[v];
            if ((k & hi_mask) == (T & hi_mask))
                atomicAdd(&hist[(k >> s) & 255], 1);
        }
        __syncthreads();
        csA[tid] = hist[255 - tid];
        __syncthreads();
        int* sb = csA; int* db = csB;
        for (int off = 1; off < 256; off <<= 1) {
            int val = sb[tid];
            if (tid >= off) val += sb[tid - off];
            db[tid] = val;
            __syncthreads();
            int* t = sb; sb = db; db = t;
        }
        {
            const int d = tid;
            int suf_d = sb[255 - d];
            int suf_d1 = (d == 255) ? 0 : sb[254 - d];
            if (suf_d >= need && suf_d1 < need) {
                sel[0] = d;
                sel[1] = suf_d1;
            }
        }
        __syncthreads();
        T |= ((unsigned)sel[0]) << s;
        need -= sel[1];
        __syncthreads();
    }

    const int wid = tid >> 6, ln = tid & 63;
    int cg = 0, ce = 0;
    for (int v = tid; v < NGRAPH; v += 256) {
        cg += (keys[v] > T) ? 1 : 0;
        ce += (keys[v] == T) ? 1 : 0;
    }
    int packed = (cg << 16) | ce;
    #pragma unroll
    for (int off = 32; off; off >>= 1) packed += __shfl_down(packed, off, 64);
    if (ln == 0) redc[wid] = packed;
    __syncthreads();
    int tot = redc[0] + redc[1] + redc[2] + redc[3];
    int m_gt = tot >> 16, m_eq = tot & 0xffff;
    int needed = KSEL - m_gt;
    float fT = (T & 0x80000000u) ? __uint_as_float(T & 0x7fffffffu)
                                 : __uint_as_float(~T);
    if (m_eq == needed || fT == 0.0f) {
        for (int v = tid; v < NGRAPH; v += 256) inc[v] = (keys[v] >= T) ? 1 : 0;
    } else {
        if (tid == 0) {
            int take = 0;
            for (int v = 0; v < NGRAPH; ++v) {
                unsigned k = keys[v];
                if (k > T) inc[v] = 1;
                else if (k == T && take < needed) { inc[v] = 1; ++take; }
                else inc[v] = 0;
            }
        }
    }
    __syncthreads();

    {
        const int rowslot = tid >> 3;
        const int c4 = tid & 7;
        float4 m4 = make_float4(-INFINITY, -INFINITY, -INFINITY, -INFINITY);
        for (int v = rowslot; v < NGRAPH; v += 32) {
            float4 hrow = ((const float4*)(h2 + (size_t)(base_n + v) * G2D))[c4];
            float sv = inc[v] ? sval[v] : 0.f;
            float big = inc[v] ? 0.f : -INFINITY;
            m4.x = fmaxf(m4.x, sv * hrow.x + big);
            m4.y = fmaxf(m4.y, sv * hrow.y + big);
            m4.z = fmaxf(m4.z, sv * hrow.z + big);
            m4.w = fmaxf(m4.w, sv * hrow.w + big);
        }
        redf[rowslot][c4 * 4 + 0] = m4.x;
        redf[rowslot][c4 * 4 + 1] = m4.y;
        redf[rowslot][c4 * 4 + 2] = m4.z;
        redf[rowslot][c4 * 4 + 3] = m4.w;
    }
    __syncthreads();
    if (tid < 32) {
        float g = redf[0][tid];
        #pragma unroll
        for (int rr = 1; rr < 32; ++rr) g = fmaxf(g, redf[rr][tid]);
        gvec[tid] = g;
    }
    __syncthreads();
    if (tid < DENSED) {
        float t = dense_b[tid];
        #pragma unroll
        for (int k = 0; k < G2D; ++k) t += gvec[k] * dense_W[k * DENSED + tid];
        dvec[tid] = fmaxf(t, 0.f);
    }
    __syncthreads();
    if (tid < NCLSD) {
        float o = out_b[tid];
        #pragma unroll
        for (int j = 0; j < DENSED; ++j) o += dvec[j] * out_W[j * NCLSD + tid];
        out[b * NCLSD + tid] = o;
    }
}

// ---------------------------------------------------------------------------
extern "C" void kernel_launch(void* const* d_in, const int* in_sizes, int n_in,
                              void* d_out, int out_size, void* d_ws, size_t ws_size,
                              hipStream_t stream)
{
    (void)in_sizes; (void)n_in; (void)out_size; (void)ws_size;
    const int*   x       = (const int*)  d_in[0];
    const int*   edge    = (const int*)  d_in[1];
    const float* emb     = (const float*)d_in[3];
    const float* W1      = (const float*)d_in[4];
    const float* b1      = (const float*)d_in[5];
    const float* W2      = (const float*)d_in[6];
    const float* b2      = (const float*)d_in[7];
    const float* pool_w  = (const float*)d_in[8];
    const float* dense_W = (const float*)d_in[9];
    const float* dense_b = (const float*)d_in[10];
    const float* out_W   = (const float*)d_in[11];
    const float* out_b   = (const float*)d_in[12];
    float* outp = (float*)d_out;

    // workspace carve-up (~53 MB)
    float* embW      = (float*)d_ws;                 // FEAT*32
    float* Abuf      = embW + FEAT * G1D;            // N*32 (A' then h2... A')
    float* Bbuf      = Abuf + (size_t)NN * G1D;      // N*32 (chist, then B')
    float* dinv      = Bbuf + (size_t)NN * G2D;      // N
    int*   row_start = (int*)(dinv + NN);            // N
    int*   csr       = row_start + NN;               // E (+16 pad)
    float* scores    = (float*)(csr + NE + 16);      // N

    int* chist = (int*)Bbuf;                         // NB*8*NGRAPH = 1024000

    prep_kernel<<<512 + (FEAT * G1D) / 256, 256, 0, stream>>>(edge, chist, emb, W1, embW);
    scan_graph<<<NB, 256, 0, stream>>>(chist, dinv, row_start);
    mid_kernel<<<512 + (NN * 8) / 1024, 1024, 0, stream>>>(edge, row_start, csr,
                                                           x, embW, dinv, Abuf);
    agg1_kernel<<<NB * 32, 256, 0, stream>>>(Abuf, dinv, row_start, csr, b1, W2, Bbuf);
    agg2_kernel<<<NB * 32, 256, 0, stream>>>(Bbuf, dinv, row_start, csr, b2, pool_w, Abuf, scores);
    topk_pool_mlp<<<NB, 256, 0, stream>>>(Abuf, scores, dense_W, dense_b, out_W, out_b, outp);
}